// Round 11
// baseline (593.097 us; speedup 1.0000x reference)
//
#include <hip/hip_runtime.h>
#include <math.h>

// Problem constants (reference: H, W, D = 96, 80, 128; KS=1 -> 27 offsets)
#define HH 96
#define WW 80
#define DD 128
#define SLICE (WW * DD)       // 10240
#define NVOX (HH * WW * DD)   // 983040

struct W4d { double w0, w1, w2, w3; };
struct Raw { float4 t[3]; float4 s[3]; };

__device__ __forceinline__ float4 zf4() { return make_float4(0.f, 0.f, 0.f, 0.f); }

// f64 2D 9-tap combine of one slice (3 rows x 6 cols incl. shfl halo) into
// P = w0*c + w1*f + w2*e and Q = w1*c + w2*f + w3*e (d^2 weight classes).
// out3d(z) = P(z) + Q(z-1) + Q(z+1), rounded once to f32 => correctly-rounded
// conv up to ~1e-16 f64 reassociation.
__device__ __forceinline__ void pq_rows(const float4 rows[3], int q, const W4d& w,
                                        double P[4], double Q[4]) {
  double d[3][6];
  #pragma unroll
  for (int r = 0; r < 3; ++r) {
    float4 v = rows[r];
    float l = __shfl_up(v.w, 1);
    float rr = __shfl_down(v.x, 1);
    if (q == 0) l = 0.f;
    if (q == 31) rr = 0.f;
    d[r][0] = (double)l;
    d[r][1] = (double)v.x;
    d[r][2] = (double)v.y;
    d[r][3] = (double)v.z;
    d[r][4] = (double)v.w;
    d[r][5] = (double)rr;
  }
  double tb[6];
  #pragma unroll
  for (int j = 0; j < 6; ++j) tb[j] = d[0][j] + d[2][j];
  #pragma unroll
  for (int i = 0; i < 4; ++i) {
    double c2 = d[1][i + 1];
    double f2 = (d[1][i] + d[1][i + 2]) + tb[i + 1];
    double e2 = tb[i] + tb[i + 2];
    P[i] = fma(w.w0, c2, fma(w.w1, f2, w.w2 * e2));
    Q[i] = fma(w.w1, c2, fma(w.w2, f2, w.w3 * e2));
  }
}

// cost-volume transform of 3 raw rows: cv = -|src(shift ox via shfl) - tgt|
__device__ __forceinline__ void cv_rows(const Raw& r, int q, int ox, float4 rows[3]) {
  #pragma unroll
  for (int dy = 0; dy < 3; ++dy) {
    float4 s4 = r.s[dy];
    float sl = __shfl_up(s4.w, 1);
    float sr = __shfl_down(s4.x, 1);
    if (q == 0) sl = 0.f;
    if (q == 31) sr = 0.f;
    float4 sh;
    if (ox < 0)      sh = make_float4(sl, s4.x, s4.y, s4.z);
    else if (ox > 0) sh = make_float4(s4.y, s4.z, s4.w, sr);
    else             sh = s4;
    float4 t4 = r.t[dy];
    rows[dy] = make_float4(-fabsf(__fsub_rn(sh.x, t4.x)), -fabsf(__fsub_rn(sh.y, t4.y)),
                           -fabsf(__fsub_rn(sh.z, t4.z)), -fabsf(__fsub_rn(sh.w, t4.w)));
  }
}

// Depthwise 3x3x3 Gaussian blur, zero padding. Thread owns 4 consecutive x
// (32 lanes = full 128-wide row, 8 rows/block), marches a z-slab with a
// 2-slice raw prefetch. Rolling f64 state: Qm(z-1), Qc(z), Pc(z).
// FUSED: computes the cost volume on the fly, channel o = blockIdx.z.
template <bool FUSED>
__global__ __launch_bounds__(256) void blur4_kernel(
    const float* __restrict__ in, const float* __restrict__ src,
    const float* __restrict__ tgt, float* __restrict__ out, int zslab, W4d w) {
  const int tid = threadIdx.x;
  const int lane = tid & 63;
  const int q = lane & 31;
  const int x0 = q << 2;
  const int y = blockIdx.x * 8 + ((tid >> 6) << 1) + (lane >> 5);
  const int c = blockIdx.z;
  const int z0 = blockIdx.y * zslab;
  const int z1 = min(z0 + zslab, HH);

  int oz = 0, oy = 0, ox = 0;
  if (FUSED) { oz = c / 9 - 1; oy = (c / 3) % 3 - 1; ox = c % 3 - 1; }
  const float* __restrict__ inc = FUSED ? (const float*)nullptr : (in + (size_t)c * NVOX);

  auto load_raw = [&](int zz, Raw& r) {
    #pragma unroll
    for (int dy = 0; dy < 3; ++dy) {
      int ry = y - 1 + dy;
      bool rv = ((unsigned)zz < (unsigned)HH) && ((unsigned)ry < (unsigned)WW);
      if (!FUSED) {
        r.t[dy] = rv ? *(const float4*)(inc + (size_t)zz * SLICE + ry * DD + x0) : zf4();
      } else {
        r.t[dy] = rv ? *(const float4*)(tgt + (size_t)zz * SLICE + ry * DD + x0) : zf4();
        int sz = zz + oz, sy = ry + oy;
        bool sv = rv && ((unsigned)sz < (unsigned)HH) && ((unsigned)sy < (unsigned)WW);
        r.s[dy] = sv ? *(const float4*)(src + (size_t)sz * SLICE + sy * DD + x0) : zf4();
      }
    }
  };

  auto finishF = [&](const Raw& r, double P[4], double Q[4]) {
    float4 rows[3];
    if (FUSED) cv_rows(r, q, ox, rows);
    else { rows[0] = r.t[0]; rows[1] = r.t[1]; rows[2] = r.t[2]; }
    pq_rows(rows, q, w, P, Q);
  };

  Raw rA, rB, rC, rD;
  load_raw(z0 - 1, rA);
  load_raw(z0, rB);
  load_raw(z0 + 1, rC);
  double Pd[4], Qm[4], Pc[4], Qc[4];
  finishF(rA, Pd, Qm);   // Pd dead -> DCE'd
  finishF(rB, Pc, Qc);
  float* ob = out + (size_t)c * NVOX + y * DD + x0;
  for (int z = z0; z < z1; ++z) {
    load_raw(z + 2, rD);          // prefetch 2 ahead
    double Pn[4], Qn[4];
    finishF(rC, Pn, Qn);
    float4 o4;
    o4.x = (float)(Pc[0] + (Qm[0] + Qn[0]));
    o4.y = (float)(Pc[1] + (Qm[1] + Qn[1]));
    o4.z = (float)(Pc[2] + (Qm[2] + Qn[2]));
    o4.w = (float)(Pc[3] + (Qm[3] + Qn[3]));
    *(float4*)(ob + (size_t)z * SLICE) = o4;
    #pragma unroll
    for (int i = 0; i < 4; ++i) { Qm[i] = Qc[i]; Qc[i] = Qn[i]; Pc[i] = Pn[i]; }
    rC = rD;
  }
}

// coupled[o] = cv[o] - coeff * ||flow - offset_o||^2 (un-fused rounds, matching
// numpy). Reference argmax = exact-equality ties on y_o = f32(coupled_o/temp);
// the division's coarse grid merges 1-ulp near-ties, which then SUM offsets.
// Running scan: strict-improve resets sums, equality adds — identical result.
// 2 voxels/thread (float2), channel loads hoisted in CHUNKS of 9 (18 VGPR):
// ~50 VGPR total -> 8 waves/SIMD AND 9-deep MLP (r8/r9/r10 showed both
// endpoints of the occupancy x MLP tradeoff lose; this is the knee).
template <int COUPLE>
__global__ __launch_bounds__(256) void flow2_kernel(
    const float* __restrict__ cv, const float* __restrict__ fin,
    float coeff, float* __restrict__ fout) {
  const int t = blockIdx.x * blockDim.x + threadIdx.x;
  const size_t v = (size_t)t * 2;
  if (v >= (size_t)NVOX) return;

  float fza[2] = {0, 0}, fya[2] = {0, 0}, fxa[2] = {0, 0};
  if (COUPLE) {
    float2 fz = *(const float2*)(fin + v);
    float2 fy = *(const float2*)(fin + (size_t)NVOX + v);
    float2 fx = *(const float2*)(fin + 2 * (size_t)NVOX + v);
    fza[0] = fz.x; fza[1] = fz.y;
    fya[0] = fy.x; fya[1] = fy.y;
    fxa[0] = fx.x; fxa[1] = fx.y;
  }
  float best[2] = {-INFINITY, -INFINITY};
  float s0[2] = {0, 0}, s1[2] = {0, 0}, s2[2] = {0, 0};

  #pragma unroll
  for (int ch = 0; ch < 3; ++ch) {           // 3 chunks of 9 channels
    float2 buf[9];
    #pragma unroll
    for (int j = 0; j < 9; ++j)
      buf[j] = *(const float2*)(cv + (size_t)(ch * 9 + j) * NVOX + v);
    #pragma unroll
    for (int j = 0; j < 9; ++j) {
      const int o = ch * 9 + j;
      const float ozf = (float)(o / 9 - 1);
      const float oyf = (float)((o / 3) % 3 - 1);
      const float oxf = (float)(o % 3 - 1);
      float ca[2] = {buf[j].x, buf[j].y};
      #pragma unroll
      for (int i = 0; i < 2; ++i) {
        float cvv = ca[i];
        if (COUPLE) {
          float dz = __fsub_rn(fza[i], ozf);
          float dy = __fsub_rn(fya[i], oyf);
          float dx = __fsub_rn(fxa[i], oxf);
          float d2 = __fadd_rn(__fadd_rn(__fmul_rn(dz, dz), __fmul_rn(dy, dy)),
                               __fmul_rn(dx, dx));
          cvv = __fsub_rn(cvv, __fmul_rn(coeff, d2));
        }
        float yv = __fdiv_rn(cvv, 5e-5f);   // tie-merging quantization step
        bool gt = yv > best[i];
        bool eq = yv == best[i];
        best[i] = gt ? yv : best[i];
        s0[i] = gt ? ozf : (eq ? s0[i] + ozf : s0[i]);
        s1[i] = gt ? oyf : (eq ? s1[i] + oyf : s1[i]);
        s2[i] = gt ? oxf : (eq ? s2[i] + oxf : s2[i]);
      }
    }
  }
  *(float2*)(fout + v) = make_float2(s0[0], s0[1]);
  *(float2*)(fout + (size_t)NVOX + v) = make_float2(s1[0], s1[1]);
  *(float2*)(fout + 2 * (size_t)NVOX + v) = make_float2(s2[0], s2[1]);
}

extern "C" void kernel_launch(void* const* d_in, const int* in_sizes, int n_in,
                              void* d_out, int out_size, void* d_ws, size_t ws_size,
                              hipStream_t stream) {
  const float* src = (const float*)d_in[0];
  const float* tgt = (const float*)d_in[1];
  float* out = (float*)d_out;

  // Workspace: cv1 27N (blurred cv, read-only after pass 3), cv2 27N (ping,
  // dead after pass 3 -> flow buffers alias there).
  float* cv1 = (float*)d_ws;
  float* cv2 = cv1 + (size_t)27 * NVOX;
  float* fa = cv2;
  float* fb = cv2 + (size_t)3 * NVOX;

  // 3^3 Gaussian (sigma=0.5) weights, replicating the reference's f32 path
  // (factor*exp in f32, numpy pairwise f32 sum, f32 divide).
  float wt[27];
  {
    volatile float factor = (float)(1.0 / pow(2.0 * M_PI * 0.25, 1.5));
    float g[27];
    int o = 0;
    for (int i = 0; i < 3; ++i)
      for (int j = 0; j < 3; ++j)
        for (int k = 0; k < 3; ++k) {
          int d2 = (i - 1) * (i - 1) + (j - 1) * (j - 1) + (k - 1) * (k - 1);
          volatile float e = (float)exp(-2.0 * (double)d2);
          volatile float gg = factor * e;
          g[o++] = gg;
        }
    volatile float r[8];
    for (int j = 0; j < 8; ++j) r[j] = g[j];
    for (int j = 0; j < 8; ++j) r[j] = r[j] + g[8 + j];
    for (int j = 0; j < 8; ++j) r[j] = r[j] + g[16 + j];
    volatile float t01 = r[0] + r[1];
    volatile float t23 = r[2] + r[3];
    volatile float t45 = r[4] + r[5];
    volatile float t67 = r[6] + r[7];
    volatile float h0 = t01 + t23;
    volatile float h1 = t45 + t67;
    volatile float s = h0 + h1;
    s = s + g[24];
    s = s + g[25];
    s = s + g[26];
    for (int t = 0; t < 27; ++t) {
      volatile float w = g[t] / s;
      wt[t] = w;
    }
  }
  // 4 distinct weight values by d^2 symmetry: center/face/edge/corner.
  W4d wd = {(double)wt[13], (double)wt[12], (double)wt[9], (double)wt[0]};

  dim3 blk(256);
  // Big: zslab=6 -> 4320 blocks; small: zslab=1 -> 2880 blocks; flow: 1920.
  dim3 gBig(WW / 8, HH / 6, 27);
  dim3 gSm(WW / 8, HH, 3);
  int fblocks = NVOX / 2 / 256;    // 1920

  // cv blur passes (pass 1 computes cv on the fly from src/tgt)
  blur4_kernel<true><<<gBig, blk, 0, stream>>>(nullptr, src, tgt, cv1, 6, wd);
  blur4_kernel<false><<<gBig, blk, 0, stream>>>(cv1, nullptr, nullptr, cv2, 6, wd);
  blur4_kernel<false><<<gBig, blk, 0, stream>>>(cv2, nullptr, nullptr, cv1, 6, wd);
  // initial argmax flow (cv2 now dead -> fa/fb live there)
  flow2_kernel<0><<<fblocks, blk, 0, stream>>>(cv1, nullptr, 0.f, fa);
  blur4_kernel<false><<<gSm, blk, 0, stream>>>(fa, nullptr, nullptr, fb, 1, wd);
  blur4_kernel<false><<<gSm, blk, 0, stream>>>(fb, nullptr, nullptr, fa, 1, wd);
  blur4_kernel<false><<<gSm, blk, 0, stream>>>(fa, nullptr, nullptr, fb, 1, wd);
  // six coupling iterations
  const float coefs[6] = {0.003f, 0.01f, 0.03f, 0.1f, 0.3f, 1.0f};
  for (int it = 0; it < 6; ++it) {
    flow2_kernel<1><<<fblocks, blk, 0, stream>>>(cv1, fb, coefs[it], fa);
    blur4_kernel<false><<<gSm, blk, 0, stream>>>(fa, nullptr, nullptr, fb, 1, wd);
    blur4_kernel<false><<<gSm, blk, 0, stream>>>(fb, nullptr, nullptr, fa, 1, wd);
    float* dst = (it == 5) ? out : fb;
    blur4_kernel<false><<<gSm, blk, 0, stream>>>(fa, nullptr, nullptr, dst, 1, wd);
  }
}

// Round 12
// 535.893 us; speedup vs baseline: 1.1067x; 1.1067x over previous
//
#include <hip/hip_runtime.h>
#include <math.h>

// Problem constants (reference: H, W, D = 96, 80, 128; KS=1 -> 27 offsets)
#define HH 96
#define WW 80
#define DD 128
#define SLICE (WW * DD)       // 10240
#define NVOX (HH * WW * DD)   // 983040

struct W4d { double w0, w1, w2, w3; };
struct Raw { float4 t[3]; float4 s[3]; };

__device__ __forceinline__ float4 zf4() { return make_float4(0.f, 0.f, 0.f, 0.f); }

// f64 2D 9-tap combine of one slice (3 rows x 6 cols incl. shfl halo) into
// P = w0*c + w1*f + w2*e and Q = w1*c + w2*f + w3*e (d^2 weight classes).
// out3d(z) = P(z) + Q(z-1) + Q(z+1), rounded once to f32 => correctly-rounded
// conv up to ~1e-16 f64 reassociation.
__device__ __forceinline__ void pq_rows(const float4 rows[3], int q, const W4d& w,
                                        double P[4], double Q[4]) {
  double d[3][6];
  #pragma unroll
  for (int r = 0; r < 3; ++r) {
    float4 v = rows[r];
    float l = __shfl_up(v.w, 1);
    float rr = __shfl_down(v.x, 1);
    if (q == 0) l = 0.f;
    if (q == 31) rr = 0.f;
    d[r][0] = (double)l;
    d[r][1] = (double)v.x;
    d[r][2] = (double)v.y;
    d[r][3] = (double)v.z;
    d[r][4] = (double)v.w;
    d[r][5] = (double)rr;
  }
  double tb[6];
  #pragma unroll
  for (int j = 0; j < 6; ++j) tb[j] = d[0][j] + d[2][j];
  #pragma unroll
  for (int i = 0; i < 4; ++i) {
    double c2 = d[1][i + 1];
    double f2 = (d[1][i] + d[1][i + 2]) + tb[i + 1];
    double e2 = tb[i] + tb[i + 2];
    P[i] = fma(w.w0, c2, fma(w.w1, f2, w.w2 * e2));
    Q[i] = fma(w.w1, c2, fma(w.w2, f2, w.w3 * e2));
  }
}

// cost-volume transform of 3 raw rows: cv = -|src(shift ox via shfl) - tgt|
__device__ __forceinline__ void cv_rows(const Raw& r, int q, int ox, float4 rows[3]) {
  #pragma unroll
  for (int dy = 0; dy < 3; ++dy) {
    float4 s4 = r.s[dy];
    float sl = __shfl_up(s4.w, 1);
    float sr = __shfl_down(s4.x, 1);
    if (q == 0) sl = 0.f;
    if (q == 31) sr = 0.f;
    float4 sh;
    if (ox < 0)      sh = make_float4(sl, s4.x, s4.y, s4.z);
    else if (ox > 0) sh = make_float4(s4.y, s4.z, s4.w, sr);
    else             sh = s4;
    float4 t4 = r.t[dy];
    rows[dy] = make_float4(-fabsf(__fsub_rn(sh.x, t4.x)), -fabsf(__fsub_rn(sh.y, t4.y)),
                           -fabsf(__fsub_rn(sh.z, t4.z)), -fabsf(__fsub_rn(sh.w, t4.w)));
  }
}

// Depthwise 3x3x3 Gaussian blur, zero padding. Thread owns 4 consecutive x
// (32 lanes = full 128-wide row, 8 rows/block), marches a z-slab with a
// 2-slice raw prefetch. Rolling f64 state: Qm(z-1), Qc(z), Pc(z).
// FUSED: computes the cost volume on the fly, channel o = blockIdx.z.
template <bool FUSED>
__global__ __launch_bounds__(256) void blur4_kernel(
    const float* __restrict__ in, const float* __restrict__ src,
    const float* __restrict__ tgt, float* __restrict__ out, int zslab, W4d w) {
  const int tid = threadIdx.x;
  const int lane = tid & 63;
  const int q = lane & 31;
  const int x0 = q << 2;
  const int y = blockIdx.x * 8 + ((tid >> 6) << 1) + (lane >> 5);
  const int c = blockIdx.z;
  const int z0 = blockIdx.y * zslab;
  const int z1 = min(z0 + zslab, HH);

  int oz = 0, oy = 0, ox = 0;
  if (FUSED) { oz = c / 9 - 1; oy = (c / 3) % 3 - 1; ox = c % 3 - 1; }
  const float* __restrict__ inc = FUSED ? (const float*)nullptr : (in + (size_t)c * NVOX);

  auto load_raw = [&](int zz, Raw& r) {
    #pragma unroll
    for (int dy = 0; dy < 3; ++dy) {
      int ry = y - 1 + dy;
      bool rv = ((unsigned)zz < (unsigned)HH) && ((unsigned)ry < (unsigned)WW);
      if (!FUSED) {
        r.t[dy] = rv ? *(const float4*)(inc + (size_t)zz * SLICE + ry * DD + x0) : zf4();
      } else {
        r.t[dy] = rv ? *(const float4*)(tgt + (size_t)zz * SLICE + ry * DD + x0) : zf4();
        int sz = zz + oz, sy = ry + oy;
        bool sv = rv && ((unsigned)sz < (unsigned)HH) && ((unsigned)sy < (unsigned)WW);
        r.s[dy] = sv ? *(const float4*)(src + (size_t)sz * SLICE + sy * DD + x0) : zf4();
      }
    }
  };

  auto finishF = [&](const Raw& r, double P[4], double Q[4]) {
    float4 rows[3];
    if (FUSED) cv_rows(r, q, ox, rows);
    else { rows[0] = r.t[0]; rows[1] = r.t[1]; rows[2] = r.t[2]; }
    pq_rows(rows, q, w, P, Q);
  };

  Raw rA, rB, rC, rD;
  load_raw(z0 - 1, rA);
  load_raw(z0, rB);
  load_raw(z0 + 1, rC);
  double Pd[4], Qm[4], Pc[4], Qc[4];
  finishF(rA, Pd, Qm);   // Pd dead -> DCE'd
  finishF(rB, Pc, Qc);
  float* ob = out + (size_t)c * NVOX + y * DD + x0;
  for (int z = z0; z < z1; ++z) {
    load_raw(z + 2, rD);          // prefetch 2 ahead
    double Pn[4], Qn[4];
    finishF(rC, Pn, Qn);
    float4 o4;
    o4.x = (float)(Pc[0] + (Qm[0] + Qn[0]));
    o4.y = (float)(Pc[1] + (Qm[1] + Qn[1]));
    o4.z = (float)(Pc[2] + (Qm[2] + Qn[2]));
    o4.w = (float)(Pc[3] + (Qm[3] + Qn[3]));
    *(float4*)(ob + (size_t)z * SLICE) = o4;
    #pragma unroll
    for (int i = 0; i < 4; ++i) { Qm[i] = Qc[i]; Qc[i] = Qn[i]; Pc[i] = Pn[i]; }
    rC = rD;
  }
}

// coupled[o] = cv[o] - coeff * ||flow - offset_o||^2 (un-fused rounds, matching
// numpy). Reference argmax = exact-equality ties on y_o = f32(coupled_o/temp);
// the division's coarse grid merges 1-ulp near-ties, which then SUM offsets.
// Tie sums tracked in ONE packed u32 per voxel (6-bit fields: cnt,
// sum(oz+1), sum(oy+1), sum(ox+1); max value 54 < 64 — exact). Integer adds
// are exact and float sums of +-1s are exact, so decode == float accumulation
// bit-exactly. 4 voxels/thread; channel loads hoisted in CHUNKS of 9
// (36 VGPR buffer — the r8/r9/r10-measured knee of occupancy x MLP).
template <int COUPLE>
__global__ __launch_bounds__(256) void flow4_kernel(
    const float* __restrict__ cv, const float* __restrict__ fin,
    float coeff, float* __restrict__ fout) {
  const int t = blockIdx.x * blockDim.x + threadIdx.x;
  const size_t v = (size_t)t * 4;
  if (v >= (size_t)NVOX) return;

  float fza[4] = {0, 0, 0, 0}, fya[4] = {0, 0, 0, 0}, fxa[4] = {0, 0, 0, 0};
  if (COUPLE) {
    float4 fz = *(const float4*)(fin + v);
    float4 fy = *(const float4*)(fin + (size_t)NVOX + v);
    float4 fx = *(const float4*)(fin + 2 * (size_t)NVOX + v);
    fza[0] = fz.x; fza[1] = fz.y; fza[2] = fz.z; fza[3] = fz.w;
    fya[0] = fy.x; fya[1] = fy.y; fya[2] = fy.z; fya[3] = fy.w;
    fxa[0] = fx.x; fxa[1] = fx.y; fxa[2] = fx.z; fxa[3] = fx.w;
  }
  float best[4] = {-INFINITY, -INFINITY, -INFINITY, -INFINITY};
  unsigned acc[4] = {0, 0, 0, 0};

  #pragma unroll
  for (int ch = 0; ch < 3; ++ch) {           // 3 chunks of 9 channels
    float4 buf[9];
    #pragma unroll
    for (int j = 0; j < 9; ++j)
      buf[j] = *(const float4*)(cv + (size_t)(ch * 9 + j) * NVOX + v);
    #pragma unroll
    for (int j = 0; j < 9; ++j) {
      const int o = ch * 9 + j;
      const float ozf = (float)(o / 9 - 1);
      const float oyf = (float)((o / 3) % 3 - 1);
      const float oxf = (float)(o % 3 - 1);
      const unsigned packed = (1u << 18) | ((unsigned)(o / 9) << 12) |
                              ((unsigned)((o / 3) % 3) << 6) | (unsigned)(o % 3);
      float ca[4] = {buf[j].x, buf[j].y, buf[j].z, buf[j].w};
      #pragma unroll
      for (int i = 0; i < 4; ++i) {
        float cvv = ca[i];
        if (COUPLE) {
          float dz = __fsub_rn(fza[i], ozf);
          float dy = __fsub_rn(fya[i], oyf);
          float dx = __fsub_rn(fxa[i], oxf);
          float d2 = __fadd_rn(__fadd_rn(__fmul_rn(dz, dz), __fmul_rn(dy, dy)),
                               __fmul_rn(dx, dx));
          cvv = __fsub_rn(cvv, __fmul_rn(coeff, d2));
        }
        float yv = __fdiv_rn(cvv, 5e-5f);   // tie-merging quantization step
        bool gt = yv > best[i];
        bool eq = yv == best[i];
        best[i] = fmaxf(best[i], yv);
        unsigned upd = eq ? acc[i] + packed : acc[i];
        acc[i] = gt ? packed : upd;
      }
    }
  }
  float s0[4], s1[4], s2[4];
  #pragma unroll
  for (int i = 0; i < 4; ++i) {
    int cnt = (int)((acc[i] >> 18) & 63u);
    s0[i] = (float)((int)((acc[i] >> 12) & 63u) - cnt);
    s1[i] = (float)((int)((acc[i] >> 6) & 63u) - cnt);
    s2[i] = (float)((int)(acc[i] & 63u) - cnt);
  }
  *(float4*)(fout + v) = make_float4(s0[0], s0[1], s0[2], s0[3]);
  *(float4*)(fout + (size_t)NVOX + v) = make_float4(s1[0], s1[1], s1[2], s1[3]);
  *(float4*)(fout + 2 * (size_t)NVOX + v) = make_float4(s2[0], s2[1], s2[2], s2[3]);
}

extern "C" void kernel_launch(void* const* d_in, const int* in_sizes, int n_in,
                              void* d_out, int out_size, void* d_ws, size_t ws_size,
                              hipStream_t stream) {
  const float* src = (const float*)d_in[0];
  const float* tgt = (const float*)d_in[1];
  float* out = (float*)d_out;

  // Workspace: cv1 27N (blurred cv, read-only after pass 3), cv2 27N (ping,
  // dead after pass 3 -> flow buffers alias there).
  float* cv1 = (float*)d_ws;
  float* cv2 = cv1 + (size_t)27 * NVOX;
  float* fa = cv2;
  float* fb = cv2 + (size_t)3 * NVOX;

  // 3^3 Gaussian (sigma=0.5) weights, replicating the reference's f32 path
  // (factor*exp in f32, numpy pairwise f32 sum, f32 divide).
  float wt[27];
  {
    volatile float factor = (float)(1.0 / pow(2.0 * M_PI * 0.25, 1.5));
    float g[27];
    int o = 0;
    for (int i = 0; i < 3; ++i)
      for (int j = 0; j < 3; ++j)
        for (int k = 0; k < 3; ++k) {
          int d2 = (i - 1) * (i - 1) + (j - 1) * (j - 1) + (k - 1) * (k - 1);
          volatile float e = (float)exp(-2.0 * (double)d2);
          volatile float gg = factor * e;
          g[o++] = gg;
        }
    volatile float r[8];
    for (int j = 0; j < 8; ++j) r[j] = g[j];
    for (int j = 0; j < 8; ++j) r[j] = r[j] + g[8 + j];
    for (int j = 0; j < 8; ++j) r[j] = r[j] + g[16 + j];
    volatile float t01 = r[0] + r[1];
    volatile float t23 = r[2] + r[3];
    volatile float t45 = r[4] + r[5];
    volatile float t67 = r[6] + r[7];
    volatile float h0 = t01 + t23;
    volatile float h1 = t45 + t67;
    volatile float s = h0 + h1;
    s = s + g[24];
    s = s + g[25];
    s = s + g[26];
    for (int t = 0; t < 27; ++t) {
      volatile float w = g[t] / s;
      wt[t] = w;
    }
  }
  // 4 distinct weight values by d^2 symmetry: center/face/edge/corner.
  W4d wd = {(double)wt[13], (double)wt[12], (double)wt[9], (double)wt[0]};

  dim3 blk(256);
  // r10 knee: big zslab=6 -> 4320 blocks; small zslab=2 -> 1440; flow 960.
  dim3 gBig(WW / 8, HH / 6, 27);
  dim3 gSm(WW / 8, HH / 2, 3);
  int fblocks = NVOX / 4 / 256;    // 960

  // cv blur passes (pass 1 computes cv on the fly from src/tgt)
  blur4_kernel<true><<<gBig, blk, 0, stream>>>(nullptr, src, tgt, cv1, 6, wd);
  blur4_kernel<false><<<gBig, blk, 0, stream>>>(cv1, nullptr, nullptr, cv2, 6, wd);
  blur4_kernel<false><<<gBig, blk, 0, stream>>>(cv2, nullptr, nullptr, cv1, 6, wd);
  // initial argmax flow (cv2 now dead -> fa/fb live there)
  flow4_kernel<0><<<fblocks, blk, 0, stream>>>(cv1, nullptr, 0.f, fa);
  blur4_kernel<false><<<gSm, blk, 0, stream>>>(fa, nullptr, nullptr, fb, 2, wd);
  blur4_kernel<false><<<gSm, blk, 0, stream>>>(fb, nullptr, nullptr, fa, 2, wd);
  blur4_kernel<false><<<gSm, blk, 0, stream>>>(fa, nullptr, nullptr, fb, 2, wd);
  // six coupling iterations
  const float coefs[6] = {0.003f, 0.01f, 0.03f, 0.1f, 0.3f, 1.0f};
  for (int it = 0; it < 6; ++it) {
    flow4_kernel<1><<<fblocks, blk, 0, stream>>>(cv1, fb, coefs[it], fa);
    blur4_kernel<false><<<gSm, blk, 0, stream>>>(fa, nullptr, nullptr, fb, 2, wd);
    blur4_kernel<false><<<gSm, blk, 0, stream>>>(fb, nullptr, nullptr, fa, 2, wd);
    float* dst = (it == 5) ? out : fb;
    blur4_kernel<false><<<gSm, blk, 0, stream>>>(fa, nullptr, nullptr, dst, 2, wd);
  }
}

// Round 13
// 531.230 us; speedup vs baseline: 1.1165x; 1.0088x over previous
//
#include <hip/hip_runtime.h>
#include <math.h>

// Problem constants (reference: H, W, D = 96, 80, 128; KS=1 -> 27 offsets)
#define HH 96
#define WW 80
#define DD 128
#define SLICE (WW * DD)       // 10240
#define NVOX (HH * WW * DD)   // 983040

struct W4d { double w0, w1, w2, w3; };
struct Raw { float4 t[3]; float4 s[3]; };

__device__ __forceinline__ float4 zf4() { return make_float4(0.f, 0.f, 0.f, 0.f); }

// f64 2D 9-tap combine of one slice (3 rows x 6 cols incl. shfl halo) into
// P = w0*c + w1*f + w2*e and Q = w1*c + w2*f + w3*e (d^2 weight classes).
// out3d(z) = P(z) + Q(z-1) + Q(z+1), rounded once to f32 => correctly-rounded
// conv up to ~1e-16 f64 reassociation.
__device__ __forceinline__ void pq_rows(const float4 rows[3], int q, const W4d& w,
                                        double P[4], double Q[4]) {
  double d[3][6];
  #pragma unroll
  for (int r = 0; r < 3; ++r) {
    float4 v = rows[r];
    float l = __shfl_up(v.w, 1);
    float rr = __shfl_down(v.x, 1);
    if (q == 0) l = 0.f;
    if (q == 31) rr = 0.f;
    d[r][0] = (double)l;
    d[r][1] = (double)v.x;
    d[r][2] = (double)v.y;
    d[r][3] = (double)v.z;
    d[r][4] = (double)v.w;
    d[r][5] = (double)rr;
  }
  double tb[6];
  #pragma unroll
  for (int j = 0; j < 6; ++j) tb[j] = d[0][j] + d[2][j];
  #pragma unroll
  for (int i = 0; i < 4; ++i) {
    double c2 = d[1][i + 1];
    double f2 = (d[1][i] + d[1][i + 2]) + tb[i + 1];
    double e2 = tb[i] + tb[i + 2];
    P[i] = fma(w.w0, c2, fma(w.w1, f2, w.w2 * e2));
    Q[i] = fma(w.w1, c2, fma(w.w2, f2, w.w3 * e2));
  }
}

// cost-volume transform of 3 raw rows: cv = -|src(shift ox via shfl) - tgt|
__device__ __forceinline__ void cv_rows(const Raw& r, int q, int ox, float4 rows[3]) {
  #pragma unroll
  for (int dy = 0; dy < 3; ++dy) {
    float4 s4 = r.s[dy];
    float sl = __shfl_up(s4.w, 1);
    float sr = __shfl_down(s4.x, 1);
    if (q == 0) sl = 0.f;
    if (q == 31) sr = 0.f;
    float4 sh;
    if (ox < 0)      sh = make_float4(sl, s4.x, s4.y, s4.z);
    else if (ox > 0) sh = make_float4(s4.y, s4.z, s4.w, sr);
    else             sh = s4;
    float4 t4 = r.t[dy];
    rows[dy] = make_float4(-fabsf(__fsub_rn(sh.x, t4.x)), -fabsf(__fsub_rn(sh.y, t4.y)),
                           -fabsf(__fsub_rn(sh.z, t4.z)), -fabsf(__fsub_rn(sh.w, t4.w)));
  }
}

// Blur body. YSAFE=true keeps the per-row y-masks (edge y-tiles); YSAFE=false
// is the mask-free fast path for interior y-tiles (y in [8,71]: all y-halos
// and even +-1 src shifts stay in-bounds). z-bounds are wave-uniform ->
// explicit uniform branches (scalar, not vector cndmask). Values and f64
// expression order identical in both paths (interior masks were all-true).
template <bool FUSED, bool YSAFE>
__device__ __forceinline__ void blur_body(
    const float* __restrict__ inc, const float* __restrict__ src,
    const float* __restrict__ tgt, float* __restrict__ outc,
    const W4d& w, int q, int x0, int y, int z0, int z1,
    int oz, int oy, int ox) {
  bool mT0 = true, mT2 = true, mS0 = true, mS1 = true, mS2 = true;
  if (YSAFE) {
    mT0 = ((unsigned)(y - 1) < (unsigned)WW);
    mT2 = ((unsigned)(y + 1) < (unsigned)WW);
    if (FUSED) {
      mS0 = mT0 && ((unsigned)(y - 1 + oy) < (unsigned)WW);
      mS1 = ((unsigned)(y + oy) < (unsigned)WW);
      mS2 = mT2 && ((unsigned)(y + 1 + oy) < (unsigned)WW);
    }
  }
  const float* __restrict__ tb_ = (FUSED ? tgt : inc) + y * DD + x0;
  const float* __restrict__ sb_ = FUSED ? (src + (y + oy) * DD + x0) : nullptr;

  auto load_raw = [&](int zz, Raw& r) {
    if ((unsigned)zz < (unsigned)HH) {          // uniform (scalar) branch
      const float* bp = tb_ + (size_t)zz * SLICE;
      r.t[0] = (!YSAFE || mT0) ? *(const float4*)(bp - DD) : zf4();
      r.t[1] = *(const float4*)bp;
      r.t[2] = (!YSAFE || mT2) ? *(const float4*)(bp + DD) : zf4();
      if (FUSED) {
        int sz = zz + oz;
        if ((unsigned)sz < (unsigned)HH) {      // uniform branch
          const float* sp = sb_ + (size_t)sz * SLICE;
          r.s[0] = (!YSAFE || mS0) ? *(const float4*)(sp - DD) : zf4();
          r.s[1] = (!YSAFE || mS1) ? *(const float4*)(sp) : zf4();
          r.s[2] = (!YSAFE || mS2) ? *(const float4*)(sp + DD) : zf4();
        } else {
          r.s[0] = zf4(); r.s[1] = zf4(); r.s[2] = zf4();
        }
      }
    } else {
      r.t[0] = zf4(); r.t[1] = zf4(); r.t[2] = zf4();
      if (FUSED) { r.s[0] = zf4(); r.s[1] = zf4(); r.s[2] = zf4(); }
    }
  };

  auto finishF = [&](const Raw& r, double P[4], double Q[4]) {
    float4 rows[3];
    if (FUSED) cv_rows(r, q, ox, rows);
    else { rows[0] = r.t[0]; rows[1] = r.t[1]; rows[2] = r.t[2]; }
    pq_rows(rows, q, w, P, Q);
  };

  Raw rA, rB, rC, rD;
  load_raw(z0 - 1, rA);
  load_raw(z0, rB);
  load_raw(z0 + 1, rC);
  double Pd[4], Qm[4], Pc[4], Qc[4];
  finishF(rA, Pd, Qm);   // Pd dead -> DCE'd
  finishF(rB, Pc, Qc);
  float* ob = outc + y * DD + x0;
  for (int z = z0; z < z1; ++z) {
    load_raw(z + 2, rD);          // prefetch 2 ahead
    double Pn[4], Qn[4];
    finishF(rC, Pn, Qn);
    float4 o4;
    o4.x = (float)(Pc[0] + (Qm[0] + Qn[0]));
    o4.y = (float)(Pc[1] + (Qm[1] + Qn[1]));
    o4.z = (float)(Pc[2] + (Qm[2] + Qn[2]));
    o4.w = (float)(Pc[3] + (Qm[3] + Qn[3]));
    *(float4*)(ob + (size_t)z * SLICE) = o4;
    #pragma unroll
    for (int i = 0; i < 4; ++i) { Qm[i] = Qc[i]; Qc[i] = Qn[i]; Pc[i] = Pn[i]; }
    rC = rD;
  }
}

// Depthwise 3x3x3 Gaussian blur wrapper: thread owns 4 consecutive x (32
// lanes = 128-wide row, 8 rows/block), marches a z-slab. Interior y-tiles
// dispatch to the mask-free body.
template <bool FUSED>
__global__ __launch_bounds__(256) void blur4_kernel(
    const float* __restrict__ in, const float* __restrict__ src,
    const float* __restrict__ tgt, float* __restrict__ out, int zslab, W4d w) {
  const int tid = threadIdx.x;
  const int lane = tid & 63;
  const int q = lane & 31;
  const int x0 = q << 2;
  const int y = blockIdx.x * 8 + ((tid >> 6) << 1) + (lane >> 5);
  const int c = blockIdx.z;
  const int z0 = blockIdx.y * zslab;
  const int z1 = min(z0 + zslab, HH);

  int oz = 0, oy = 0, ox = 0;
  if (FUSED) { oz = c / 9 - 1; oy = (c / 3) % 3 - 1; ox = c % 3 - 1; }
  const float* __restrict__ inc = FUSED ? (const float*)nullptr : (in + (size_t)c * NVOX);
  float* __restrict__ outc = out + (size_t)c * NVOX;

  const bool interior = (blockIdx.x > 0) && (blockIdx.x + 1 < gridDim.x);
  if (interior)
    blur_body<FUSED, false>(inc, src, tgt, outc, w, q, x0, y, z0, z1, oz, oy, ox);
  else
    blur_body<FUSED, true>(inc, src, tgt, outc, w, q, x0, y, z0, z1, oz, oy, ox);
}

// coupled[o] = cv[o] - coeff * ||flow - offset_o||^2 (un-fused rounds, matching
// numpy). Reference argmax = exact-equality ties on y_o = f32(coupled_o/temp);
// the division's coarse grid merges 1-ulp near-ties, which then SUM offsets.
// Tie sums tracked in ONE packed u32 (6-bit fields; exact). 4 voxels/thread;
// channel loads hoisted in CHUNKS of 9 (the r8-r10-measured occupancy x MLP knee).
template <int COUPLE>
__global__ __launch_bounds__(256) void flow4_kernel(
    const float* __restrict__ cv, const float* __restrict__ fin,
    float coeff, float* __restrict__ fout) {
  const int t = blockIdx.x * blockDim.x + threadIdx.x;
  const size_t v = (size_t)t * 4;
  if (v >= (size_t)NVOX) return;

  float fza[4] = {0, 0, 0, 0}, fya[4] = {0, 0, 0, 0}, fxa[4] = {0, 0, 0, 0};
  if (COUPLE) {
    float4 fz = *(const float4*)(fin + v);
    float4 fy = *(const float4*)(fin + (size_t)NVOX + v);
    float4 fx = *(const float4*)(fin + 2 * (size_t)NVOX + v);
    fza[0] = fz.x; fza[1] = fz.y; fza[2] = fz.z; fza[3] = fz.w;
    fya[0] = fy.x; fya[1] = fy.y; fya[2] = fy.z; fya[3] = fy.w;
    fxa[0] = fx.x; fxa[1] = fx.y; fxa[2] = fx.z; fxa[3] = fx.w;
  }
  float best[4] = {-INFINITY, -INFINITY, -INFINITY, -INFINITY};
  unsigned acc[4] = {0, 0, 0, 0};

  #pragma unroll
  for (int ch = 0; ch < 3; ++ch) {           // 3 chunks of 9 channels
    float4 buf[9];
    #pragma unroll
    for (int j = 0; j < 9; ++j)
      buf[j] = *(const float4*)(cv + (size_t)(ch * 9 + j) * NVOX + v);
    #pragma unroll
    for (int j = 0; j < 9; ++j) {
      const int o = ch * 9 + j;
      const float ozf = (float)(o / 9 - 1);
      const float oyf = (float)((o / 3) % 3 - 1);
      const float oxf = (float)(o % 3 - 1);
      const unsigned packed = (1u << 18) | ((unsigned)(o / 9) << 12) |
                              ((unsigned)((o / 3) % 3) << 6) | (unsigned)(o % 3);
      float ca[4] = {buf[j].x, buf[j].y, buf[j].z, buf[j].w};
      #pragma unroll
      for (int i = 0; i < 4; ++i) {
        float cvv = ca[i];
        if (COUPLE) {
          float dz = __fsub_rn(fza[i], ozf);
          float dy = __fsub_rn(fya[i], oyf);
          float dx = __fsub_rn(fxa[i], oxf);
          float d2 = __fadd_rn(__fadd_rn(__fmul_rn(dz, dz), __fmul_rn(dy, dy)),
                               __fmul_rn(dx, dx));
          cvv = __fsub_rn(cvv, __fmul_rn(coeff, d2));
        }
        float yv = __fdiv_rn(cvv, 5e-5f);   // tie-merging quantization step
        bool gt = yv > best[i];
        bool eq = yv == best[i];
        best[i] = fmaxf(best[i], yv);
        unsigned upd = eq ? acc[i] + packed : acc[i];
        acc[i] = gt ? packed : upd;
      }
    }
  }
  float s0[4], s1[4], s2[4];
  #pragma unroll
  for (int i = 0; i < 4; ++i) {
    int cnt = (int)((acc[i] >> 18) & 63u);
    s0[i] = (float)((int)((acc[i] >> 12) & 63u) - cnt);
    s1[i] = (float)((int)((acc[i] >> 6) & 63u) - cnt);
    s2[i] = (float)((int)(acc[i] & 63u) - cnt);
  }
  *(float4*)(fout + v) = make_float4(s0[0], s0[1], s0[2], s0[3]);
  *(float4*)(fout + (size_t)NVOX + v) = make_float4(s1[0], s1[1], s1[2], s1[3]);
  *(float4*)(fout + 2 * (size_t)NVOX + v) = make_float4(s2[0], s2[1], s2[2], s2[3]);
}

extern "C" void kernel_launch(void* const* d_in, const int* in_sizes, int n_in,
                              void* d_out, int out_size, void* d_ws, size_t ws_size,
                              hipStream_t stream) {
  const float* src = (const float*)d_in[0];
  const float* tgt = (const float*)d_in[1];
  float* out = (float*)d_out;

  // Workspace: cv1 27N (blurred cv, read-only after pass 3), cv2 27N (ping,
  // dead after pass 3 -> flow buffers alias there).
  float* cv1 = (float*)d_ws;
  float* cv2 = cv1 + (size_t)27 * NVOX;
  float* fa = cv2;
  float* fb = cv2 + (size_t)3 * NVOX;

  // 3^3 Gaussian (sigma=0.5) weights, replicating the reference's f32 path
  // (factor*exp in f32, numpy pairwise f32 sum, f32 divide).
  float wt[27];
  {
    volatile float factor = (float)(1.0 / pow(2.0 * M_PI * 0.25, 1.5));
    float g[27];
    int o = 0;
    for (int i = 0; i < 3; ++i)
      for (int j = 0; j < 3; ++j)
        for (int k = 0; k < 3; ++k) {
          int d2 = (i - 1) * (i - 1) + (j - 1) * (j - 1) + (k - 1) * (k - 1);
          volatile float e = (float)exp(-2.0 * (double)d2);
          volatile float gg = factor * e;
          g[o++] = gg;
        }
    volatile float r[8];
    for (int j = 0; j < 8; ++j) r[j] = g[j];
    for (int j = 0; j < 8; ++j) r[j] = r[j] + g[8 + j];
    for (int j = 0; j < 8; ++j) r[j] = r[j] + g[16 + j];
    volatile float t01 = r[0] + r[1];
    volatile float t23 = r[2] + r[3];
    volatile float t45 = r[4] + r[5];
    volatile float t67 = r[6] + r[7];
    volatile float h0 = t01 + t23;
    volatile float h1 = t45 + t67;
    volatile float s = h0 + h1;
    s = s + g[24];
    s = s + g[25];
    s = s + g[26];
    for (int t = 0; t < 27; ++t) {
      volatile float w = g[t] / s;
      wt[t] = w;
    }
  }
  // 4 distinct weight values by d^2 symmetry: center/face/edge/corner.
  W4d wd = {(double)wt[13], (double)wt[12], (double)wt[9], (double)wt[0]};

  dim3 blk(256);
  // r10 knee: big zslab=6 -> 4320 blocks; small zslab=2 -> 1440; flow 960.
  dim3 gBig(WW / 8, HH / 6, 27);
  dim3 gSm(WW / 8, HH / 2, 3);
  int fblocks = NVOX / 4 / 256;    // 960

  // cv blur passes (pass 1 computes cv on the fly from src/tgt)
  blur4_kernel<true><<<gBig, blk, 0, stream>>>(nullptr, src, tgt, cv1, 6, wd);
  blur4_kernel<false><<<gBig, blk, 0, stream>>>(cv1, nullptr, nullptr, cv2, 6, wd);
  blur4_kernel<false><<<gBig, blk, 0, stream>>>(cv2, nullptr, nullptr, cv1, 6, wd);
  // initial argmax flow (cv2 now dead -> fa/fb live there)
  flow4_kernel<0><<<fblocks, blk, 0, stream>>>(cv1, nullptr, 0.f, fa);
  blur4_kernel<false><<<gSm, blk, 0, stream>>>(fa, nullptr, nullptr, fb, 2, wd);
  blur4_kernel<false><<<gSm, blk, 0, stream>>>(fb, nullptr, nullptr, fa, 2, wd);
  blur4_kernel<false><<<gSm, blk, 0, stream>>>(fa, nullptr, nullptr, fb, 2, wd);
  // six coupling iterations
  const float coefs[6] = {0.003f, 0.01f, 0.03f, 0.1f, 0.3f, 1.0f};
  for (int it = 0; it < 6; ++it) {
    flow4_kernel<1><<<fblocks, blk, 0, stream>>>(cv1, fb, coefs[it], fa);
    blur4_kernel<false><<<gSm, blk, 0, stream>>>(fa, nullptr, nullptr, fb, 2, wd);
    blur4_kernel<false><<<gSm, blk, 0, stream>>>(fb, nullptr, nullptr, fa, 2, wd);
    float* dst = (it == 5) ? out : fb;
    blur4_kernel<false><<<gSm, blk, 0, stream>>>(fa, nullptr, nullptr, dst, 2, wd);
  }
}